// Round 1
// baseline (5108.539 us; speedup 1.0000x reference)
//
#include <hip/hip_runtime.h>
#include <math.h>

// ---------------------------------------------------------------------------
// VisionMambaDenoiser: patch-embed -> mamba block -> deconv -> 3x3 conv
// Round 0: correctness-first fp32 implementation.
// ---------------------------------------------------------------------------

#define BM 64
#define BN 64
#define BK 16
#define LDT 68   // padded LDS leading dim: breaks 16-way bank conflict on tile
                 // stores while keeping 16B alignment for float4 reads

// C[m,n] = act( sum_k A[m*lda+k] * W[n*ldw+k] + bias[n/bias_div] )
// act: 0 = none, 1 = relu, 2 = softplus
__global__ __launch_bounds__(256) void gemm_atb(
    const float* __restrict__ A, const float* __restrict__ W,
    float* __restrict__ C, const float* __restrict__ bias,
    int M, int N, int K, int lda, int ldw, int ldc,
    int bias_div, int act)
{
    __shared__ float As[BK][LDT];
    __shared__ float Ws[BK][LDT];
    const int tid = threadIdx.x;
    const int tm = tid >> 4;    // 0..15
    const int tn = tid & 15;    // 0..15
    const int m0 = blockIdx.y * BM;
    const int n0 = blockIdx.x * BN;
    float acc[4][4] = {};

    for (int k0 = 0; k0 < K; k0 += BK) {
        #pragma unroll
        for (int s = 0; s < 4; ++s) {
            int i = tid + s * 256;          // 0..1023
            int kk = i & 15;                // k fastest -> coalesced global read
            int rr = i >> 4;                // 0..63
            int m = m0 + rr;
            int n = n0 + rr;
            int k = k0 + kk;
            As[kk][rr] = (m < M && k < K) ? A[(size_t)m * lda + k] : 0.f;
            Ws[kk][rr] = (n < N && k < K) ? W[(size_t)n * ldw + k] : 0.f;
        }
        __syncthreads();
        #pragma unroll
        for (int kk = 0; kk < BK; ++kk) {
            float a[4], w[4];
            #pragma unroll
            for (int i = 0; i < 4; ++i) a[i] = As[kk][tm * 4 + i];
            #pragma unroll
            for (int j = 0; j < 4; ++j) w[j] = Ws[kk][tn * 4 + j];
            #pragma unroll
            for (int i = 0; i < 4; ++i)
                #pragma unroll
                for (int j = 0; j < 4; ++j)
                    acc[i][j] += a[i] * w[j];
        }
        __syncthreads();
    }

    #pragma unroll
    for (int i = 0; i < 4; ++i) {
        int m = m0 + tm * 4 + i;
        if (m >= M) continue;
        #pragma unroll
        for (int j = 0; j < 4; ++j) {
            int n = n0 + tn * 4 + j;
            if (n >= N) continue;
            float v = acc[i][j];
            if (bias) v += bias[n / bias_div];
            if (act == 1) v = fmaxf(v, 0.f);
            else if (act == 2) v = (v > 20.f) ? v : log1pf(expf(v));
            C[(size_t)m * ldc + n] = v;
        }
    }
}

// x (8,3,512,512) -> P[(b*1024 + h*32 + w), (c*256 + p*16 + q)]  (8192 x 768)
__global__ __launch_bounds__(256) void im2col_patch(const float* __restrict__ x,
                                                    float* __restrict__ P)
{
    int idx = blockIdx.x * 256 + threadIdx.x;   // exactly 8192*768 threads
    int col = idx % 768;
    int row = idx / 768;
    int b = row >> 10;
    int l = row & 1023;
    int h = l >> 5, w = l & 31;
    int c = col >> 8;
    int p = (col >> 4) & 15, q = col & 15;
    P[idx] = x[((size_t)(b * 3 + c) * 512 + (h * 16 + p)) * 512 + (w * 16 + q)];
}

// depthwise causal conv1d (left pad 3) + bias + silu
// xz (8192,768): u_raw = cols [0,384). Writes u (8192,384).
__global__ __launch_bounds__(256) void conv1d_silu(const float* __restrict__ xz,
                                                   const float* __restrict__ cw,
                                                   const float* __restrict__ cb,
                                                   float* __restrict__ u)
{
    int idx = blockIdx.x * 256 + threadIdx.x;   // exactly 8192*384
    int d = idx % 384;
    int row = idx / 384;    // b*1024 + l
    int l = row & 1023;
    float acc = cb[d];
    #pragma unroll
    for (int j = 0; j < 4; ++j) {
        int ll = l - 3 + j;
        if (ll >= 0) acc += xz[(size_t)(row - 3 + j) * 768 + d] * cw[d * 4 + j];
    }
    u[idx] = acc / (1.f + expf(-acc));          // silu
}

// Selective scan. 16 lanes per (b,d) channel; lane = state index n.
// y[b,l,d] = (sum_n h_n*C_n + u*D[d]) * silu(z)
__global__ __launch_bounds__(256) void ssm_scan(const float* __restrict__ delta,
                                                const float* __restrict__ dbc,
                                                const float* __restrict__ u,
                                                const float* __restrict__ xz,
                                                const float* __restrict__ A_log,
                                                const float* __restrict__ Dp,
                                                float* __restrict__ y)
{
    int t = blockIdx.x * 256 + threadIdx.x;     // exactly 8*384*16
    int n = t & 15;
    int gid = t >> 4;
    int b = gid / 384;
    int d = gid % 384;
    float A = -expf(A_log[d * 16 + n]);
    float Dv = Dp[d];
    float h = 0.f;
    const float* drow  = delta + (size_t)(b * 1024) * 384 + d;
    const float* dbcr  = dbc   + (size_t)(b * 1024) * 44;
    const float* urow  = u     + (size_t)(b * 1024) * 384 + d;
    const float* zrow  = xz    + (size_t)(b * 1024) * 768 + 384 + d;
    float* yrow        = y     + (size_t)(b * 1024) * 384 + d;

    for (int l = 0; l < 1024; ++l) {
        float dl = drow[(size_t)l * 384];
        float ul = urow[(size_t)l * 384];
        float Bn = dbcr[l * 44 + 12 + n];
        float Cn = dbcr[l * 44 + 28 + n];
        float a = expf(dl * A);
        h = a * h + dl * Bn * ul;
        float part = h * Cn;
        part += __shfl_xor(part, 1, 16);
        part += __shfl_xor(part, 2, 16);
        part += __shfl_xor(part, 4, 16);
        part += __shfl_xor(part, 8, 16);
        if (n == 0) {
            float zl = zrow[(size_t)l * 768];
            float sz = zl / (1.f + expf(-zl));
            yrow[(size_t)l * 384] = (part + ul * Dv) * sz;
        }
    }
}

// deconv_w (192,64,16,16) -> W2[(k*256+p*16+q), c]   (16384 x 192)
__global__ __launch_bounds__(256) void transpose_w(const float* __restrict__ src,
                                                   float* __restrict__ dst)
{
    int idx = blockIdx.x * 256 + threadIdx.x;   // exactly 16384*192
    int c = idx % 192;
    int r = idx / 192;
    dst[idx] = src[(size_t)c * 16384 + r];
}

// dec_conv_w (3,64,3,3) -> dwr[((co*3+dy)*3+dx)*64 + k]
__global__ void rearrange_dcw(const float* __restrict__ src, float* __restrict__ dst)
{
    int i = blockIdx.x * 256 + threadIdx.x;
    if (i >= 1728) return;
    int k = i & 63;
    int r = i >> 6;            // co*9 + dy*3 + dx
    int co = r / 9;
    int dydx = r % 9;
    int dy = dydx / 3, dx = dydx % 3;
    dst[i] = src[((co * 64 + k) * 3 + dy) * 3 + dx];
}

// Fused 3x3 conv (64->3, pad 1) + bias + sigmoid over the per-batch deconv slab.
// Db[(h*32+w), k*256 + p*16 + q] holds relu(deconv) for batch b.
// One block = one 16x16 output patch; d reads hit L1/L2 (9x reuse by neighbors).
__global__ __launch_bounds__(256) void decconv_sigmoid(const float* __restrict__ Db,
                                                       const float* __restrict__ dwr,
                                                       const float* __restrict__ dcb,
                                                       float* __restrict__ out,
                                                       int b)
{
    int px = threadIdx.x & 15, py = threadIdx.x >> 4;
    int Y = blockIdx.y * 16 + py;
    int X = blockIdx.x * 16 + px;
    float acc0 = dcb[0], acc1 = dcb[1], acc2 = dcb[2];
    const float4* dwr4 = (const float4*)dwr;

    #pragma unroll
    for (int dy = 0; dy < 3; ++dy) {
        int Yn = Y + dy - 1;
        bool yok = (unsigned)Yn < 512u;
        int hh = Yn >> 4, pp = Yn & 15;
        #pragma unroll
        for (int dx = 0; dx < 3; ++dx) {
            int Xn = X + dx - 1;
            bool ok = yok && ((unsigned)Xn < 512u);
            int ww = Xn >> 4, qq = Xn & 15;
            const float* dptr = Db + ((size_t)(hh * 32 + ww) * 16384 + pp * 16 + qq);
            #pragma unroll
            for (int k4 = 0; k4 < 16; ++k4) {
                // weight reads are wave-uniform -> scalar loads / K$-cached
                float4 w0 = dwr4[(0 * 9 + dy * 3 + dx) * 16 + k4];
                float4 w1 = dwr4[(1 * 9 + dy * 3 + dx) * 16 + k4];
                float4 w2 = dwr4[(2 * 9 + dy * 3 + dx) * 16 + k4];
                #pragma unroll
                for (int kk = 0; kk < 4; ++kk) {
                    int k = k4 * 4 + kk;
                    float v = ok ? dptr[(size_t)k * 256] : 0.f;
                    float wa = (kk == 0) ? w0.x : (kk == 1) ? w0.y : (kk == 2) ? w0.z : w0.w;
                    float wb = (kk == 0) ? w1.x : (kk == 1) ? w1.y : (kk == 2) ? w1.z : w1.w;
                    float wc = (kk == 0) ? w2.x : (kk == 1) ? w2.y : (kk == 2) ? w2.z : w2.w;
                    acc0 += v * wa;
                    acc1 += v * wb;
                    acc2 += v * wc;
                }
            }
        }
    }
    size_t o = ((size_t)(b * 3) * 512 + Y) * 512 + X;
    out[o]                 = 1.f / (1.f + expf(-acc0));
    out[o + 512 * 512]     = 1.f / (1.f + expf(-acc1));
    out[o + 2 * 512 * 512] = 1.f / (1.f + expf(-acc2));
}

// ---------------------------------------------------------------------------
// Workspace layout (floats). Db aliases the front region (all dead by then).
// Total: 22,021,824 floats = 88.1 MB
// ---------------------------------------------------------------------------
#define WS_P        0            // 8192*768  = 6291456  (im2col; dead after patch gemm)
#define WS_SEQ      6291456      // 8192*192  = 1572864  (dead after in_proj)
#define WS_XZ       7864320      // 8192*768  = 6291456  (z half live until scan)
#define WS_U        14155776     // 8192*384  = 3145728  (live until scan)
#define WS_DELTA    0            // 8192*384  = 3145728  (aliases dead P)
#define WS_DBC      3145728      // 8192*44   = 360448
#define WS_Y        3506176      // 8192*384  = 3145728  (ends 6651904 < WS_XZ)
#define WS_SEQOUT   17301504     // 8192*192  = 1572864
#define WS_W2       18874368     // 16384*192 = 3145728
#define WS_DWR      22020096     // 1728
#define WS_DB       0            // 1024*16384 = 16777216 (aliases everything dead)

extern "C" void kernel_launch(void* const* d_in, const int* in_sizes, int n_in,
                              void* d_out, int out_size, void* d_ws, size_t ws_size,
                              hipStream_t stream)
{
    const float* x         = (const float*)d_in[0];
    const float* patch_w   = (const float*)d_in[1];
    const float* patch_b   = (const float*)d_in[2];
    const float* in_proj_w = (const float*)d_in[3];
    const float* conv1d_w  = (const float*)d_in[4];
    const float* conv1d_b  = (const float*)d_in[5];
    const float* x_proj_w  = (const float*)d_in[6];
    const float* dt_proj_w = (const float*)d_in[7];
    const float* dt_proj_b = (const float*)d_in[8];
    const float* A_log     = (const float*)d_in[9];
    const float* Dp        = (const float*)d_in[10];
    const float* out_proj_w= (const float*)d_in[11];
    const float* deconv_w  = (const float*)d_in[12];
    const float* deconv_b  = (const float*)d_in[13];
    const float* dec_conv_w= (const float*)d_in[14];
    const float* dec_conv_b= (const float*)d_in[15];
    float* out = (float*)d_out;
    float* ws  = (float*)d_ws;

    float* P      = ws + WS_P;
    float* seq    = ws + WS_SEQ;
    float* xz     = ws + WS_XZ;
    float* u      = ws + WS_U;
    float* delta  = ws + WS_DELTA;
    float* dbc    = ws + WS_DBC;
    float* y      = ws + WS_Y;
    float* seqo   = ws + WS_SEQOUT;
    float* W2     = ws + WS_W2;
    float* dwr    = ws + WS_DWR;
    float* Db     = ws + WS_DB;

    // 1. im2col of input patches
    im2col_patch<<<24576, 256, 0, stream>>>(x, P);
    // 2. patch embedding: (8192,768) @ (192,768)^T + patch_b -> seq (8192,192)
    gemm_atb<<<dim3(3, 128), 256, 0, stream>>>(P, patch_w, seq, patch_b,
                                               8192, 192, 768, 768, 768, 192, 1, 0);
    // 3. in_proj: (8192,192) @ (768,192)^T -> xz (8192,768)
    gemm_atb<<<dim3(12, 128), 256, 0, stream>>>(seq, in_proj_w, xz, nullptr,
                                                8192, 768, 192, 192, 192, 768, 1, 0);
    // 4. depthwise causal conv1d + silu -> u (8192,384)
    conv1d_silu<<<12288, 256, 0, stream>>>(xz, conv1d_w, conv1d_b, u);
    // 5. x_proj: (8192,384) @ (44,384)^T -> dbc (8192,44)
    gemm_atb<<<dim3(1, 128), 256, 0, stream>>>(u, x_proj_w, dbc, nullptr,
                                               8192, 44, 384, 384, 384, 44, 1, 0);
    // 6. dt_proj + softplus: dbc[:, :12] @ (384,12)^T + dt_b -> delta (8192,384)
    gemm_atb<<<dim3(6, 128), 256, 0, stream>>>(dbc, dt_proj_w, delta, dt_proj_b,
                                               8192, 384, 12, 44, 12, 384, 1, 2);
    // 7. selective scan -> y (8192,384)  (includes +u*D and *silu(z))
    ssm_scan<<<192, 256, 0, stream>>>(delta, dbc, u, xz, A_log, Dp, y);
    // 8. out_proj: (8192,384) @ (192,384)^T -> seqo (8192,192)
    gemm_atb<<<dim3(3, 128), 256, 0, stream>>>(y, out_proj_w, seqo, nullptr,
                                               8192, 192, 384, 384, 384, 192, 1, 0);
    // 9. weight reshuffles for the decoder
    transpose_w<<<12288, 256, 0, stream>>>(deconv_w, W2);
    rearrange_dcw<<<7, 256, 0, stream>>>(dec_conv_w, dwr);
    // 10. per-batch: deconv GEMM (+bias+relu) -> Db ; fused 3x3 conv + sigmoid
    for (int b = 0; b < 8; ++b) {
        gemm_atb<<<dim3(256, 16), 256, 0, stream>>>(seqo + (size_t)b * 1024 * 192, W2,
                                                    Db, deconv_b,
                                                    1024, 16384, 192, 192, 192, 16384,
                                                    256, 1);
        decconv_sigmoid<<<dim3(32, 32), 256, 0, stream>>>(Db, dwr, dec_conv_b, out, b);
    }
}

// Round 2
// 3986.119 us; speedup vs baseline: 1.2816x; 1.2816x over previous
//
#include <hip/hip_runtime.h>
#include <math.h>

// ---------------------------------------------------------------------------
// VisionMambaDenoiser. Round 1: chunked parallel scan + bf16 MFMA deconv GEMM.
// ---------------------------------------------------------------------------

#define BM 64
#define BN 64
#define BK 16
#define LDT 68

typedef short bf16x8 __attribute__((ext_vector_type(8)));
typedef float f32x4 __attribute__((ext_vector_type(4)));

__device__ inline unsigned short f2bf(float f) {
    unsigned int u = __float_as_uint(f);
    unsigned int r = (u + 0x7fff + ((u >> 16) & 1)) >> 16;   // RNE
    return (unsigned short)r;
}

// ---------------- generic fp32 GEMM: C = act(A @ W^T + bias) ----------------
__global__ __launch_bounds__(256) void gemm_atb(
    const float* __restrict__ A, const float* __restrict__ W,
    float* __restrict__ C, const float* __restrict__ bias,
    int M, int N, int K, int lda, int ldw, int ldc,
    int bias_div, int act)
{
    __shared__ float As[BK][LDT];
    __shared__ float Ws[BK][LDT];
    const int tid = threadIdx.x;
    const int tm = tid >> 4;
    const int tn = tid & 15;
    const int m0 = blockIdx.y * BM;
    const int n0 = blockIdx.x * BN;
    float acc[4][4] = {};

    for (int k0 = 0; k0 < K; k0 += BK) {
        #pragma unroll
        for (int s = 0; s < 4; ++s) {
            int i = tid + s * 256;
            int kk = i & 15;
            int rr = i >> 4;
            int m = m0 + rr;
            int n = n0 + rr;
            int k = k0 + kk;
            As[kk][rr] = (m < M && k < K) ? A[(size_t)m * lda + k] : 0.f;
            Ws[kk][rr] = (n < N && k < K) ? W[(size_t)n * ldw + k] : 0.f;
        }
        __syncthreads();
        #pragma unroll
        for (int kk = 0; kk < BK; ++kk) {
            float a[4], w[4];
            #pragma unroll
            for (int i = 0; i < 4; ++i) a[i] = As[kk][tm * 4 + i];
            #pragma unroll
            for (int j = 0; j < 4; ++j) w[j] = Ws[kk][tn * 4 + j];
            #pragma unroll
            for (int i = 0; i < 4; ++i)
                #pragma unroll
                for (int j = 0; j < 4; ++j)
                    acc[i][j] += a[i] * w[j];
        }
        __syncthreads();
    }

    #pragma unroll
    for (int i = 0; i < 4; ++i) {
        int m = m0 + tm * 4 + i;
        if (m >= M) continue;
        #pragma unroll
        for (int j = 0; j < 4; ++j) {
            int n = n0 + tn * 4 + j;
            if (n >= N) continue;
            float v = acc[i][j];
            if (bias) v += bias[n / bias_div];
            if (act == 1) v = fmaxf(v, 0.f);
            else if (act == 2) v = (v > 20.f) ? v : log1pf(expf(v));
            C[(size_t)m * ldc + n] = v;
        }
    }
}

// ---------------- bf16 MFMA GEMM for the deconv: C = relu(A @ W^T + bias) ---
// A (M,K) bf16 row-major, W (N,K) bf16 row-major, C (M,N) fp32.
// M=1024, N=16384, K=192. Tile 128x128, BK=32, 4 waves, 4x4 MFMA grid/wave.
__global__ __launch_bounds__(256) void gemm_mfma_relu(
    const unsigned short* __restrict__ A, const unsigned short* __restrict__ W,
    float* __restrict__ C, const float* __restrict__ bias,
    int M, int N, int K)
{
    __shared__ unsigned short As[128][48];   // pad to 48 (96B rows, 16B-aligned)
    __shared__ unsigned short Bs[128][48];
    const int tid = threadIdx.x;
    const int wave = tid >> 6;
    const int lane = tid & 63;
    const int wm = (wave & 1) * 64;
    const int wn = (wave >> 1) * 64;
    const int m0 = blockIdx.y * 128;
    const int n0 = blockIdx.x * 128;
    const int quad = lane >> 4;
    const int lr = lane & 15;

    f32x4 acc[4][4];
    #pragma unroll
    for (int i = 0; i < 4; ++i)
        #pragma unroll
        for (int j = 0; j < 4; ++j)
            acc[i][j] = (f32x4){0.f, 0.f, 0.f, 0.f};

    const int r = tid >> 2, kq = tid & 3;
    for (int k0 = 0; k0 < K; k0 += 32) {
        #pragma unroll
        for (int half = 0; half < 2; ++half) {
            int rr = r + half * 64;
            *(float4*)(&As[rr][kq * 8]) =
                *(const float4*)(A + (size_t)(m0 + rr) * K + k0 + kq * 8);
            *(float4*)(&Bs[rr][kq * 8]) =
                *(const float4*)(W + (size_t)(n0 + rr) * K + k0 + kq * 8);
        }
        __syncthreads();
        bf16x8 af[4], bfr[4];
        #pragma unroll
        for (int i = 0; i < 4; ++i) af[i] = *(const bf16x8*)(&As[wm + i * 16 + lr][quad * 8]);
        #pragma unroll
        for (int j = 0; j < 4; ++j) bfr[j] = *(const bf16x8*)(&Bs[wn + j * 16 + lr][quad * 8]);
        #pragma unroll
        for (int i = 0; i < 4; ++i)
            #pragma unroll
            for (int j = 0; j < 4; ++j)
                acc[i][j] = __builtin_amdgcn_mfma_f32_16x16x32_bf16(af[i], bfr[j], acc[i][j], 0, 0, 0);
        __syncthreads();
    }

    #pragma unroll
    for (int i = 0; i < 4; ++i) {
        int gm = m0 + wm + i * 16 + quad * 4;
        #pragma unroll
        for (int j = 0; j < 4; ++j) {
            int gn = n0 + wn + j * 16 + lr;
            float bv = bias[gn >> 8];
            #pragma unroll
            for (int rr = 0; rr < 4; ++rr) {
                float v = acc[i][j][rr] + bv;
                C[(size_t)(gm + rr) * N + gn] = fmaxf(v, 0.f);
            }
        }
    }
}

// ---------------- im2col of 16x16 patches -----------------------------------
__global__ __launch_bounds__(256) void im2col_patch(const float* __restrict__ x,
                                                    float* __restrict__ P)
{
    int idx = blockIdx.x * 256 + threadIdx.x;
    int col = idx % 768;
    int row = idx / 768;
    int b = row >> 10;
    int l = row & 1023;
    int h = l >> 5, w = l & 31;
    int c = col >> 8;
    int p = (col >> 4) & 15, q = col & 15;
    P[idx] = x[((size_t)(b * 3 + c) * 512 + (h * 16 + p)) * 512 + (w * 16 + q)];
}

// ---------------- depthwise causal conv1d + silu ----------------------------
__global__ __launch_bounds__(256) void conv1d_silu(const float* __restrict__ xz,
                                                   const float* __restrict__ cw,
                                                   const float* __restrict__ cb,
                                                   float* __restrict__ u)
{
    int idx = blockIdx.x * 256 + threadIdx.x;
    int d = idx % 384;
    int row = idx / 384;
    int l = row & 1023;
    float acc = cb[d];
    #pragma unroll
    for (int j = 0; j < 4; ++j) {
        int ll = l - 3 + j;
        if (ll >= 0) acc += xz[(size_t)(row - 3 + j) * 768 + d] * cw[d * 4 + j];
    }
    u[idx] = acc / (1.f + expf(-acc));
}

// ---------------- selective scan: 3-pass chunked linear recurrence ----------
// Chunking: L=1024 -> 8 chunks of 128. Thread t = ((b*384+d)*8 + c)*16 + n.
__global__ __launch_bounds__(256) void ssm_pass1(const float* __restrict__ delta,
                                                 const float* __restrict__ dbc,
                                                 const float* __restrict__ u,
                                                 const float* __restrict__ A_log,
                                                 float* __restrict__ Pc,
                                                 float* __restrict__ Hc)
{
    int t = blockIdx.x * 256 + threadIdx.x;    // 8*384*8*16 = 393216
    int n = t & 15;
    int c = (t >> 4) & 7;
    int gid = t >> 7;                          // b*384 + d
    int b = gid / 384, d = gid % 384;
    float A = -__expf(A_log[d * 16 + n]);
    const float* drow = delta + (size_t)(b * 1024) * 384 + d;
    const float* urow = u     + (size_t)(b * 1024) * 384 + d;
    const float* dbcr = dbc   + (size_t)(b * 1024) * 44;
    float P = 1.f, H = 0.f;
    int l0 = c * 128;
    for (int l = l0; l < l0 + 128; ++l) {
        float dl = drow[(size_t)l * 384];
        float ul = urow[(size_t)l * 384];
        float Bn = dbcr[l * 44 + 12 + n];
        float a = __expf(dl * A);
        P *= a;
        H = a * H + dl * Bn * ul;
    }
    Pc[t] = P;
    Hc[t] = H;
}

__global__ __launch_bounds__(256) void ssm_pass2(const float* __restrict__ Pc,
                                                 const float* __restrict__ Hc,
                                                 float* __restrict__ h0c)
{
    int t = blockIdx.x * 256 + threadIdx.x;    // 8*384*16 = 49152
    int n = t & 15;
    int gid = t >> 4;
    float h = 0.f;
    #pragma unroll
    for (int c = 0; c < 8; ++c) {
        int idx = (gid * 8 + c) * 16 + n;
        h0c[idx] = h;
        h = Pc[idx] * h + Hc[idx];
    }
}

__global__ __launch_bounds__(256) void ssm_pass3(const float* __restrict__ delta,
                                                 const float* __restrict__ dbc,
                                                 const float* __restrict__ u,
                                                 const float* __restrict__ xz,
                                                 const float* __restrict__ A_log,
                                                 const float* __restrict__ Dp,
                                                 const float* __restrict__ h0c,
                                                 float* __restrict__ y)
{
    int t = blockIdx.x * 256 + threadIdx.x;    // 393216
    int n = t & 15;
    int c = (t >> 4) & 7;
    int gid = t >> 7;
    int b = gid / 384, d = gid % 384;
    float A = -__expf(A_log[d * 16 + n]);
    float Dv = Dp[d];
    const float* drow = delta + (size_t)(b * 1024) * 384 + d;
    const float* urow = u     + (size_t)(b * 1024) * 384 + d;
    const float* dbcr = dbc   + (size_t)(b * 1024) * 44;
    const float* zrow = xz    + (size_t)(b * 1024) * 768 + 384 + d;
    float* yrow       = y     + (size_t)(b * 1024) * 384 + d;
    float h = h0c[t];
    int l0 = c * 128;
    for (int l = l0; l < l0 + 128; ++l) {
        float dl = drow[(size_t)l * 384];
        float ul = urow[(size_t)l * 384];
        float Bn = dbcr[l * 44 + 12 + n];
        float Cn = dbcr[l * 44 + 28 + n];
        float a = __expf(dl * A);
        h = a * h + dl * Bn * ul;
        float part = h * Cn;
        part += __shfl_xor(part, 1, 16);
        part += __shfl_xor(part, 2, 16);
        part += __shfl_xor(part, 4, 16);
        part += __shfl_xor(part, 8, 16);
        if (n == 0) {
            float zl = zrow[(size_t)l * 768];
            float sz = zl / (1.f + __expf(-zl));
            yrow[(size_t)l * 384] = (part + ul * Dv) * sz;
        }
    }
}

// ---------------- fp32 -> bf16 convert (vector 4) ---------------------------
__global__ __launch_bounds__(256) void f32_to_bf16_vec(const float* __restrict__ src,
                                                       unsigned short* __restrict__ dst)
{
    int i = blockIdx.x * 256 + threadIdx.x;    // n/4 threads
    float4 v = ((const float4*)src)[i];
    ushort4 o;
    o.x = f2bf(v.x); o.y = f2bf(v.y); o.z = f2bf(v.z); o.w = f2bf(v.w);
    ((ushort4*)dst)[i] = o;
}

// deconv_w (192,64,16,16) fp32 -> W2b[(k*256+p*16+q), c] bf16  (16384 x 192)
__global__ __launch_bounds__(256) void transpose_w_bf16(const float* __restrict__ src,
                                                        unsigned short* __restrict__ dst)
{
    int idx = blockIdx.x * 256 + threadIdx.x;  // 16384*192
    int c = idx % 192;
    int r = idx / 192;
    dst[idx] = f2bf(src[(size_t)c * 16384 + r]);
}

// dec_conv_w (3,64,3,3) -> dwr[((co*3+dy)*3+dx)*64 + k]
__global__ void rearrange_dcw(const float* __restrict__ src, float* __restrict__ dst)
{
    int i = blockIdx.x * 256 + threadIdx.x;
    if (i >= 1728) return;
    int k = i & 63;
    int r = i >> 6;
    int co = r / 9;
    int dydx = r % 9;
    int dy = dydx / 3, dx = dydx % 3;
    dst[i] = src[((co * 64 + k) * 3 + dy) * 3 + dx];
}

// ---------------- fused 3x3 conv (64->3) + bias + sigmoid -------------------
__global__ __launch_bounds__(256) void decconv_sigmoid(const float* __restrict__ Db,
                                                       const float* __restrict__ dwr,
                                                       const float* __restrict__ dcb,
                                                       float* __restrict__ out,
                                                       int b)
{
    int px = threadIdx.x & 15, py = threadIdx.x >> 4;
    int Y = blockIdx.y * 16 + py;
    int X = blockIdx.x * 16 + px;
    float acc0 = dcb[0], acc1 = dcb[1], acc2 = dcb[2];
    const float4* dwr4 = (const float4*)dwr;

    #pragma unroll
    for (int dy = 0; dy < 3; ++dy) {
        int Yn = Y + dy - 1;
        bool yok = (unsigned)Yn < 512u;
        int hh = Yn >> 4, pp = Yn & 15;
        #pragma unroll
        for (int dx = 0; dx < 3; ++dx) {
            int Xn = X + dx - 1;
            bool ok = yok && ((unsigned)Xn < 512u);
            int ww = Xn >> 4, qq = Xn & 15;
            const float* dptr = Db + ((size_t)(hh * 32 + ww) * 16384 + pp * 16 + qq);
            #pragma unroll
            for (int k4 = 0; k4 < 16; ++k4) {
                float4 w0 = dwr4[(0 * 9 + dy * 3 + dx) * 16 + k4];
                float4 w1 = dwr4[(1 * 9 + dy * 3 + dx) * 16 + k4];
                float4 w2 = dwr4[(2 * 9 + dy * 3 + dx) * 16 + k4];
                #pragma unroll
                for (int kk = 0; kk < 4; ++kk) {
                    int k = k4 * 4 + kk;
                    float v = ok ? dptr[(size_t)k * 256] : 0.f;
                    float wa = (kk == 0) ? w0.x : (kk == 1) ? w0.y : (kk == 2) ? w0.z : w0.w;
                    float wb = (kk == 0) ? w1.x : (kk == 1) ? w1.y : (kk == 2) ? w1.z : w1.w;
                    float wc = (kk == 0) ? w2.x : (kk == 1) ? w2.y : (kk == 2) ? w2.z : w2.w;
                    acc0 += v * wa;
                    acc1 += v * wb;
                    acc2 += v * wc;
                }
            }
        }
    }
    size_t o = ((size_t)(b * 3) * 512 + Y) * 512 + X;
    out[o]                 = 1.f / (1.f + expf(-acc0));
    out[o + 512 * 512]     = 1.f / (1.f + expf(-acc1));
    out[o + 2 * 512 * 512] = 1.f / (1.f + expf(-acc2));
}

// ---------------------------------------------------------------------------
// Workspace layout (float units). Total 22,021,824 floats = 88.1 MB.
// ---------------------------------------------------------------------------
#define WS_P        0            // im2col (dead after patch gemm)
#define WS_SEQ      6291456      // dead after in_proj; tail reused for scan scratch
#define WS_XZ       7864320
#define WS_U        14155776
#define WS_DELTA    0            // aliases dead P
#define WS_DBC      3145728
#define WS_Y        3506176      // ends 6651904
#define WS_PC       6651904      // 393216 (scan scratch; seq dead)
#define WS_HC       7045120      // 393216
#define WS_H0C      7438336      // 393216 (ends 7831552 < WS_XZ)
#define WS_SEQOUT   17301504
#define WS_W2       18874368     // bf16 storage (uses half the old fp32 region)
#define WS_DWR      22020096
#define WS_DB       0            // 16777216 (aliases all dead by decode time)
#define WS_SEQO_BF  16777216     // 786432 ushorts = 393216 floats (< 17301504)

extern "C" void kernel_launch(void* const* d_in, const int* in_sizes, int n_in,
                              void* d_out, int out_size, void* d_ws, size_t ws_size,
                              hipStream_t stream)
{
    const float* x         = (const float*)d_in[0];
    const float* patch_w   = (const float*)d_in[1];
    const float* patch_b   = (const float*)d_in[2];
    const float* in_proj_w = (const float*)d_in[3];
    const float* conv1d_w  = (const float*)d_in[4];
    const float* conv1d_b  = (const float*)d_in[5];
    const float* x_proj_w  = (const float*)d_in[6];
    const float* dt_proj_w = (const float*)d_in[7];
    const float* dt_proj_b = (const float*)d_in[8];
    const float* A_log     = (const float*)d_in[9];
    const float* Dp        = (const float*)d_in[10];
    const float* out_proj_w= (const float*)d_in[11];
    const float* deconv_w  = (const float*)d_in[12];
    const float* deconv_b  = (const float*)d_in[13];
    const float* dec_conv_w= (const float*)d_in[14];
    const float* dec_conv_b= (const float*)d_in[15];
    float* out = (float*)d_out;
    float* ws  = (float*)d_ws;

    float* P      = ws + WS_P;
    float* seq    = ws + WS_SEQ;
    float* xz     = ws + WS_XZ;
    float* u      = ws + WS_U;
    float* delta  = ws + WS_DELTA;
    float* dbc    = ws + WS_DBC;
    float* y      = ws + WS_Y;
    float* Pc     = ws + WS_PC;
    float* Hc     = ws + WS_HC;
    float* h0c    = ws + WS_H0C;
    float* seqo   = ws + WS_SEQOUT;
    unsigned short* W2b    = (unsigned short*)(ws + WS_W2);
    float* dwr    = ws + WS_DWR;
    float* Db     = ws + WS_DB;
    unsigned short* seqo_b = (unsigned short*)(ws + WS_SEQO_BF);

    // 1. im2col
    im2col_patch<<<24576, 256, 0, stream>>>(x, P);
    // 2. patch embedding
    gemm_atb<<<dim3(3, 128), 256, 0, stream>>>(P, patch_w, seq, patch_b,
                                               8192, 192, 768, 768, 768, 192, 1, 0);
    // 3. in_proj
    gemm_atb<<<dim3(12, 128), 256, 0, stream>>>(seq, in_proj_w, xz, nullptr,
                                                8192, 768, 192, 192, 192, 768, 1, 0);
    // 4. conv1d + silu
    conv1d_silu<<<12288, 256, 0, stream>>>(xz, conv1d_w, conv1d_b, u);
    // 5. x_proj
    gemm_atb<<<dim3(1, 128), 256, 0, stream>>>(u, x_proj_w, dbc, nullptr,
                                               8192, 44, 384, 384, 384, 44, 1, 0);
    // 6. dt_proj + softplus
    gemm_atb<<<dim3(6, 128), 256, 0, stream>>>(dbc, dt_proj_w, delta, dt_proj_b,
                                               8192, 384, 12, 44, 12, 384, 1, 2);
    // 7. selective scan: 3-pass chunked
    ssm_pass1<<<1536, 256, 0, stream>>>(delta, dbc, u, A_log, Pc, Hc);
    ssm_pass2<<<192, 256, 0, stream>>>(Pc, Hc, h0c);
    ssm_pass3<<<1536, 256, 0, stream>>>(delta, dbc, u, xz, A_log, Dp, h0c, y);
    // 8. out_proj
    gemm_atb<<<dim3(3, 128), 256, 0, stream>>>(y, out_proj_w, seqo, nullptr,
                                               8192, 192, 384, 384, 384, 192, 1, 0);
    // 9. decoder weight prep + seqo -> bf16
    f32_to_bf16_vec<<<1536, 256, 0, stream>>>(seqo, seqo_b);       // 8192*192/4
    transpose_w_bf16<<<12288, 256, 0, stream>>>(deconv_w, W2b);
    rearrange_dcw<<<7, 256, 0, stream>>>(dec_conv_w, dwr);
    // 10. per-batch: bf16 MFMA deconv GEMM (+bias+relu) -> fused conv+sigmoid
    for (int b = 0; b < 8; ++b) {
        gemm_mfma_relu<<<dim3(128, 8), 256, 0, stream>>>(seqo_b + (size_t)b * 1024 * 192,
                                                         W2b, Db, deconv_b,
                                                         1024, 16384, 192);
        decconv_sigmoid<<<dim3(32, 32), 256, 0, stream>>>(Db, dwr, dec_conv_b, out, b);
    }
}

// Round 3
// 1089.953 us; speedup vs baseline: 4.6869x; 3.6571x over previous
//
#include <hip/hip_runtime.h>
#include <math.h>

// ---------------------------------------------------------------------------
// VisionMambaDenoiser. Round 2: rebuilt decoder — bf16 pixel-major Db slab +
// LDS-staged halo conv (was 6.7x refetch, latency-bound, 92% of runtime).
// ---------------------------------------------------------------------------

#define BM 64
#define BN 64
#define BK 16
#define LDT 68

typedef short bf16x8 __attribute__((ext_vector_type(8)));
typedef float f32x4 __attribute__((ext_vector_type(4)));

__device__ inline unsigned short f2bf(float f) {
    unsigned int u = __float_as_uint(f);
    unsigned int r = (u + 0x7fff + ((u >> 16) & 1)) >> 16;   // RNE
    return (unsigned short)r;
}

// ---------------- generic fp32 GEMM: C = act(A @ W^T + bias) ----------------
__global__ __launch_bounds__(256) void gemm_atb(
    const float* __restrict__ A, const float* __restrict__ W,
    float* __restrict__ C, const float* __restrict__ bias,
    int M, int N, int K, int lda, int ldw, int ldc,
    int bias_div, int act)
{
    __shared__ float As[BK][LDT];
    __shared__ float Ws[BK][LDT];
    const int tid = threadIdx.x;
    const int tm = tid >> 4;
    const int tn = tid & 15;
    const int m0 = blockIdx.y * BM;
    const int n0 = blockIdx.x * BN;
    float acc[4][4] = {};

    for (int k0 = 0; k0 < K; k0 += BK) {
        #pragma unroll
        for (int s = 0; s < 4; ++s) {
            int i = tid + s * 256;
            int kk = i & 15;
            int rr = i >> 4;
            int m = m0 + rr;
            int n = n0 + rr;
            int k = k0 + kk;
            As[kk][rr] = (m < M && k < K) ? A[(size_t)m * lda + k] : 0.f;
            Ws[kk][rr] = (n < N && k < K) ? W[(size_t)n * ldw + k] : 0.f;
        }
        __syncthreads();
        #pragma unroll
        for (int kk = 0; kk < BK; ++kk) {
            float a[4], w[4];
            #pragma unroll
            for (int i = 0; i < 4; ++i) a[i] = As[kk][tm * 4 + i];
            #pragma unroll
            for (int j = 0; j < 4; ++j) w[j] = Ws[kk][tn * 4 + j];
            #pragma unroll
            for (int i = 0; i < 4; ++i)
                #pragma unroll
                for (int j = 0; j < 4; ++j)
                    acc[i][j] += a[i] * w[j];
        }
        __syncthreads();
    }

    #pragma unroll
    for (int i = 0; i < 4; ++i) {
        int m = m0 + tm * 4 + i;
        if (m >= M) continue;
        #pragma unroll
        for (int j = 0; j < 4; ++j) {
            int n = n0 + tn * 4 + j;
            if (n >= N) continue;
            float v = acc[i][j];
            if (bias) v += bias[n / bias_div];
            if (act == 1) v = fmaxf(v, 0.f);
            else if (act == 2) v = (v > 20.f) ? v : log1pf(expf(v));
            C[(size_t)m * ldc + n] = v;
        }
    }
}

// ---------------- bf16 MFMA GEMM: Db = bf16(relu(A @ W^T + bias[k])) --------
// A (M,K) bf16, W (N,K) bf16 with row order n = (p*16+q)*64 + k.
// C bf16 (M,N). M=1024, N=16384, K=192.
__global__ __launch_bounds__(256) void gemm_mfma_relu_bf16(
    const unsigned short* __restrict__ A, const unsigned short* __restrict__ W,
    unsigned short* __restrict__ C, const float* __restrict__ bias,
    int M, int N, int K)
{
    __shared__ unsigned short As[128][48];
    __shared__ unsigned short Bs[128][48];
    const int tid = threadIdx.x;
    const int wave = tid >> 6;
    const int lane = tid & 63;
    const int wm = (wave & 1) * 64;
    const int wn = (wave >> 1) * 64;
    const int m0 = blockIdx.y * 128;
    const int n0 = blockIdx.x * 128;
    const int quad = lane >> 4;
    const int lr = lane & 15;

    f32x4 acc[4][4];
    #pragma unroll
    for (int i = 0; i < 4; ++i)
        #pragma unroll
        for (int j = 0; j < 4; ++j)
            acc[i][j] = (f32x4){0.f, 0.f, 0.f, 0.f};

    const int r = tid >> 2, kq = tid & 3;
    for (int k0 = 0; k0 < K; k0 += 32) {
        #pragma unroll
        for (int half = 0; half < 2; ++half) {
            int rr = r + half * 64;
            *(float4*)(&As[rr][kq * 8]) =
                *(const float4*)(A + (size_t)(m0 + rr) * K + k0 + kq * 8);
            *(float4*)(&Bs[rr][kq * 8]) =
                *(const float4*)(W + (size_t)(n0 + rr) * K + k0 + kq * 8);
        }
        __syncthreads();
        bf16x8 af[4], bfr[4];
        #pragma unroll
        for (int i = 0; i < 4; ++i) af[i] = *(const bf16x8*)(&As[wm + i * 16 + lr][quad * 8]);
        #pragma unroll
        for (int j = 0; j < 4; ++j) bfr[j] = *(const bf16x8*)(&Bs[wn + j * 16 + lr][quad * 8]);
        #pragma unroll
        for (int i = 0; i < 4; ++i)
            #pragma unroll
            for (int j = 0; j < 4; ++j)
                acc[i][j] = __builtin_amdgcn_mfma_f32_16x16x32_bf16(af[i], bfr[j], acc[i][j], 0, 0, 0);
        __syncthreads();
    }

    #pragma unroll
    for (int i = 0; i < 4; ++i) {
        int gm = m0 + wm + i * 16 + quad * 4;
        #pragma unroll
        for (int j = 0; j < 4; ++j) {
            int gn = n0 + wn + j * 16 + lr;
            float bv = bias[gn & 63];          // k = n & 63 in the new row order
            #pragma unroll
            for (int rr = 0; rr < 4; ++rr) {
                float v = fmaxf(acc[i][j][rr] + bv, 0.f);
                C[(size_t)(gm + rr) * N + gn] = f2bf(v);
            }
        }
    }
}

// ---------------- im2col of 16x16 patches -----------------------------------
__global__ __launch_bounds__(256) void im2col_patch(const float* __restrict__ x,
                                                    float* __restrict__ P)
{
    int idx = blockIdx.x * 256 + threadIdx.x;
    int col = idx % 768;
    int row = idx / 768;
    int b = row >> 10;
    int l = row & 1023;
    int h = l >> 5, w = l & 31;
    int c = col >> 8;
    int p = (col >> 4) & 15, q = col & 15;
    P[idx] = x[((size_t)(b * 3 + c) * 512 + (h * 16 + p)) * 512 + (w * 16 + q)];
}

// ---------------- depthwise causal conv1d + silu ----------------------------
__global__ __launch_bounds__(256) void conv1d_silu(const float* __restrict__ xz,
                                                   const float* __restrict__ cw,
                                                   const float* __restrict__ cb,
                                                   float* __restrict__ u)
{
    int idx = blockIdx.x * 256 + threadIdx.x;
    int d = idx % 384;
    int row = idx / 384;
    int l = row & 1023;
    float acc = cb[d];
    #pragma unroll
    for (int j = 0; j < 4; ++j) {
        int ll = l - 3 + j;
        if (ll >= 0) acc += xz[(size_t)(row - 3 + j) * 768 + d] * cw[d * 4 + j];
    }
    u[idx] = acc / (1.f + expf(-acc));
}

// ---------------- selective scan: 3-pass chunked linear recurrence ----------
__global__ __launch_bounds__(256) void ssm_pass1(const float* __restrict__ delta,
                                                 const float* __restrict__ dbc,
                                                 const float* __restrict__ u,
                                                 const float* __restrict__ A_log,
                                                 float* __restrict__ Pc,
                                                 float* __restrict__ Hc)
{
    int t = blockIdx.x * 256 + threadIdx.x;    // 393216
    int n = t & 15;
    int c = (t >> 4) & 7;
    int gid = t >> 7;
    int b = gid / 384, d = gid % 384;
    float A = -__expf(A_log[d * 16 + n]);
    const float* drow = delta + (size_t)(b * 1024) * 384 + d;
    const float* urow = u     + (size_t)(b * 1024) * 384 + d;
    const float* dbcr = dbc   + (size_t)(b * 1024) * 44;
    float P = 1.f, H = 0.f;
    int l0 = c * 128;
    for (int l = l0; l < l0 + 128; ++l) {
        float dl = drow[(size_t)l * 384];
        float ul = urow[(size_t)l * 384];
        float Bn = dbcr[l * 44 + 12 + n];
        float a = __expf(dl * A);
        P *= a;
        H = a * H + dl * Bn * ul;
    }
    Pc[t] = P;
    Hc[t] = H;
}

__global__ __launch_bounds__(256) void ssm_pass2(const float* __restrict__ Pc,
                                                 const float* __restrict__ Hc,
                                                 float* __restrict__ h0c)
{
    int t = blockIdx.x * 256 + threadIdx.x;    // 49152
    int n = t & 15;
    int gid = t >> 4;
    float h = 0.f;
    #pragma unroll
    for (int c = 0; c < 8; ++c) {
        int idx = (gid * 8 + c) * 16 + n;
        h0c[idx] = h;
        h = Pc[idx] * h + Hc[idx];
    }
}

__global__ __launch_bounds__(256) void ssm_pass3(const float* __restrict__ delta,
                                                 const float* __restrict__ dbc,
                                                 const float* __restrict__ u,
                                                 const float* __restrict__ xz,
                                                 const float* __restrict__ A_log,
                                                 const float* __restrict__ Dp,
                                                 const float* __restrict__ h0c,
                                                 float* __restrict__ y)
{
    int t = blockIdx.x * 256 + threadIdx.x;
    int n = t & 15;
    int c = (t >> 4) & 7;
    int gid = t >> 7;
    int b = gid / 384, d = gid % 384;
    float A = -__expf(A_log[d * 16 + n]);
    float Dv = Dp[d];
    const float* drow = delta + (size_t)(b * 1024) * 384 + d;
    const float* urow = u     + (size_t)(b * 1024) * 384 + d;
    const float* dbcr = dbc   + (size_t)(b * 1024) * 44;
    const float* zrow = xz    + (size_t)(b * 1024) * 768 + 384 + d;
    float* yrow       = y     + (size_t)(b * 1024) * 384 + d;
    float h = h0c[t];
    int l0 = c * 128;
    for (int l = l0; l < l0 + 128; ++l) {
        float dl = drow[(size_t)l * 384];
        float ul = urow[(size_t)l * 384];
        float Bn = dbcr[l * 44 + 12 + n];
        float Cn = dbcr[l * 44 + 28 + n];
        float a = __expf(dl * A);
        h = a * h + dl * Bn * ul;
        float part = h * Cn;
        part += __shfl_xor(part, 1, 16);
        part += __shfl_xor(part, 2, 16);
        part += __shfl_xor(part, 4, 16);
        part += __shfl_xor(part, 8, 16);
        if (n == 0) {
            float zl = zrow[(size_t)l * 768];
            float sz = zl / (1.f + __expf(-zl));
            yrow[(size_t)l * 384] = (part + ul * Dv) * sz;
        }
    }
}

// ---------------- fp32 -> bf16 convert --------------------------------------
__global__ __launch_bounds__(256) void f32_to_bf16_vec(const float* __restrict__ src,
                                                       unsigned short* __restrict__ dst)
{
    int i = blockIdx.x * 256 + threadIdx.x;
    float4 v = ((const float4*)src)[i];
    ushort4 o;
    o.x = f2bf(v.x); o.y = f2bf(v.y); o.z = f2bf(v.z); o.w = f2bf(v.w);
    ((ushort4*)dst)[i] = o;
}

// deconv_w (192,64,16,16) fp32 -> W2b[n'][c] bf16, n' = (p*16+q)*64 + k
__global__ __launch_bounds__(256) void transpose_w_bf16(const float* __restrict__ src,
                                                        unsigned short* __restrict__ dst)
{
    int idx = blockIdx.x * 256 + threadIdx.x;  // 16384*192
    int c = idx % 192;
    int np = idx / 192;
    int k = np & 63;
    int pq = np >> 6;
    dst[idx] = f2bf(src[(size_t)c * 16384 + k * 256 + pq]);
}

// dec_conv_w (3,64,3,3) -> dwr[((co*3+dy)*3+dx)*64 + k]
__global__ void rearrange_dcw(const float* __restrict__ src, float* __restrict__ dst)
{
    int i = blockIdx.x * 256 + threadIdx.x;
    if (i >= 1728) return;
    int k = i & 63;
    int r = i >> 6;
    int co = r / 9;
    int dydx = r % 9;
    int dy = dydx / 3, dx = dydx % 3;
    dst[i] = src[((co * 64 + k) * 3 + dy) * 3 + dx];
}

// ---------------- LDS-staged 3x3 conv (64->3) + bias + sigmoid --------------
// One block per 16x16 patch. Db bf16 layout: [patch][(p*16+q)*64 + k].
// LDS tile 18x18 pixels x 64 ch (k padded to 72 for bank spread).
__global__ __launch_bounds__(256) void decconv_sigmoid2(
    const unsigned short* __restrict__ Db, const float* __restrict__ dwr,
    const float* __restrict__ dcb, float* __restrict__ out, int b)
{
    __shared__ unsigned short ds[18 * 18 * 72];
    const int t = threadIdx.x;
    const int pidx = blockIdx.x;            // h*32 + w
    const int ph = pidx >> 5, pw = pidx & 31;
    const uint4 z4 = {0, 0, 0, 0};

    // center 16x16x64 (32 KB contiguous)
    const unsigned short* base = Db + ((size_t)pidx << 14);
    #pragma unroll
    for (int s = 0; s < 8; ++s) {
        int f = s * 256 + t;
        int k8 = f & 7, pq = f >> 3;
        int p = pq >> 4, q = pq & 15;
        *(uint4*)&ds[((p + 1) * 18 + q + 1) * 72 + k8 * 8] =
            *(const uint4*)(base + pq * 64 + k8 * 8);
    }
    // halo edges
    {
        int k8 = t & 7, e = (t >> 3) & 15;
        if (t < 128) {        // top: neighbor (ph-1), its p=15 row
            uint4 v = z4;
            if (ph > 0) v = *(const uint4*)(Db + ((size_t)(pidx - 32) << 14) + (240 + e) * 64 + k8 * 8);
            *(uint4*)&ds[(0 * 18 + e + 1) * 72 + k8 * 8] = v;
        } else {              // bottom: neighbor (ph+1), its p=0 row
            uint4 v = z4;
            if (ph < 31) v = *(const uint4*)(Db + ((size_t)(pidx + 32) << 14) + e * 64 + k8 * 8);
            *(uint4*)&ds[(17 * 18 + e + 1) * 72 + k8 * 8] = v;
        }
        if (t < 128) {        // left: neighbor (pw-1), its q=15 column
            uint4 v = z4;
            if (pw > 0) v = *(const uint4*)(Db + ((size_t)(pidx - 1) << 14) + (e * 16 + 15) * 64 + k8 * 8);
            *(uint4*)&ds[((e + 1) * 18 + 0) * 72 + k8 * 8] = v;
        } else {              // right: neighbor (pw+1), its q=0 column
            uint4 v = z4;
            if (pw < 31) v = *(const uint4*)(Db + ((size_t)(pidx + 1) << 14) + (e * 16) * 64 + k8 * 8);
            *(uint4*)&ds[((e + 1) * 18 + 17) * 72 + k8 * 8] = v;
        }
        if (t < 32) {         // 4 corners
            int c = t >> 3;
            int dh = (c >> 1) * 2 - 1, dw = (c & 1) * 2 - 1;
            int nh = ph + dh, nw = pw + dw;
            int sp = dh < 0 ? 15 : 0, sq = dw < 0 ? 15 : 0;
            uint4 v = z4;
            if (nh >= 0 && nh < 32 && nw >= 0 && nw < 32)
                v = *(const uint4*)(Db + ((size_t)(nh * 32 + nw) << 14) + (sp * 16 + sq) * 64 + k8 * 8);
            int dy = dh < 0 ? 0 : 17, dx = dw < 0 ? 0 : 17;
            *(uint4*)&ds[(dy * 18 + dx) * 72 + k8 * 8] = v;
        }
    }
    __syncthreads();

    const int px = t & 15, py = t >> 4;
    float a0 = dcb[0], a1 = dcb[1], a2 = dcb[2];
    for (int dy = 0; dy < 3; ++dy)
        for (int dx = 0; dx < 3; ++dx) {
            const unsigned short* cell = &ds[((py + dy) * 18 + (px + dx)) * 72];
            const float* w0 = dwr + (0 * 9 + dy * 3 + dx) * 64;
            const float* w1 = dwr + (1 * 9 + dy * 3 + dx) * 64;
            const float* w2 = dwr + (2 * 9 + dy * 3 + dx) * 64;
            #pragma unroll
            for (int k8 = 0; k8 < 8; ++k8) {
                uint4 v = *(const uint4*)(cell + k8 * 8);
                unsigned int uu[4] = {v.x, v.y, v.z, v.w};
                #pragma unroll
                for (int m = 0; m < 4; ++m) {
                    float flo = __uint_as_float(uu[m] << 16);
                    float fhi = __uint_as_float(uu[m] & 0xffff0000u);
                    int k = k8 * 8 + m * 2;
                    a0 += flo * w0[k] + fhi * w0[k + 1];
                    a1 += flo * w1[k] + fhi * w1[k + 1];
                    a2 += flo * w2[k] + fhi * w2[k + 1];
                }
            }
        }

    int Y = ph * 16 + py, X = pw * 16 + px;
    size_t o = (size_t)(b * 3) * 262144 + (size_t)Y * 512 + X;
    out[o]          = 1.f / (1.f + __expf(-a0));
    out[o + 262144] = 1.f / (1.f + __expf(-a1));
    out[o + 524288] = 1.f / (1.f + __expf(-a2));
}

// ---------------------------------------------------------------------------
// Workspace layout (float units). Total 22,021,824 floats = 88.1 MB.
// Db (bf16, 16.8M ushorts = 8.4M floats) aliases [0, 8388608): delta/dbc/y/
// scan scratch/xz are all dead by decode time.
// ---------------------------------------------------------------------------
#define WS_P        0
#define WS_SEQ      6291456
#define WS_XZ       7864320
#define WS_U        14155776
#define WS_DELTA    0
#define WS_DBC      3145728
#define WS_Y        3506176
#define WS_PC       6651904
#define WS_HC       7045120
#define WS_H0C      7438336
#define WS_SEQOUT   17301504
#define WS_W2       18874368
#define WS_DWR      22020096
#define WS_DB       0
#define WS_SEQO_BF  16777216

extern "C" void kernel_launch(void* const* d_in, const int* in_sizes, int n_in,
                              void* d_out, int out_size, void* d_ws, size_t ws_size,
                              hipStream_t stream)
{
    const float* x         = (const float*)d_in[0];
    const float* patch_w   = (const float*)d_in[1];
    const float* patch_b   = (const float*)d_in[2];
    const float* in_proj_w = (const float*)d_in[3];
    const float* conv1d_w  = (const float*)d_in[4];
    const float* conv1d_b  = (const float*)d_in[5];
    const float* x_proj_w  = (const float*)d_in[6];
    const float* dt_proj_w = (const float*)d_in[7];
    const float* dt_proj_b = (const float*)d_in[8];
    const float* A_log     = (const float*)d_in[9];
    const float* Dp        = (const float*)d_in[10];
    const float* out_proj_w= (const float*)d_in[11];
    const float* deconv_w  = (const float*)d_in[12];
    const float* deconv_b  = (const float*)d_in[13];
    const float* dec_conv_w= (const float*)d_in[14];
    const float* dec_conv_b= (const float*)d_in[15];
    float* out = (float*)d_out;
    float* ws  = (float*)d_ws;

    float* P      = ws + WS_P;
    float* seq    = ws + WS_SEQ;
    float* xz     = ws + WS_XZ;
    float* u      = ws + WS_U;
    float* delta  = ws + WS_DELTA;
    float* dbc    = ws + WS_DBC;
    float* y      = ws + WS_Y;
    float* Pc     = ws + WS_PC;
    float* Hc     = ws + WS_HC;
    float* h0c    = ws + WS_H0C;
    float* seqo   = ws + WS_SEQOUT;
    unsigned short* W2b    = (unsigned short*)(ws + WS_W2);
    float* dwr    = ws + WS_DWR;
    unsigned short* Db16   = (unsigned short*)(ws + WS_DB);
    unsigned short* seqo_b = (unsigned short*)(ws + WS_SEQO_BF);

    // 1. im2col
    im2col_patch<<<24576, 256, 0, stream>>>(x, P);
    // 2. patch embedding
    gemm_atb<<<dim3(3, 128), 256, 0, stream>>>(P, patch_w, seq, patch_b,
                                               8192, 192, 768, 768, 768, 192, 1, 0);
    // 3. in_proj
    gemm_atb<<<dim3(12, 128), 256, 0, stream>>>(seq, in_proj_w, xz, nullptr,
                                                8192, 768, 192, 192, 192, 768, 1, 0);
    // 4. conv1d + silu
    conv1d_silu<<<12288, 256, 0, stream>>>(xz, conv1d_w, conv1d_b, u);
    // 5. x_proj
    gemm_atb<<<dim3(1, 128), 256, 0, stream>>>(u, x_proj_w, dbc, nullptr,
                                               8192, 44, 384, 384, 384, 44, 1, 0);
    // 6. dt_proj + softplus
    gemm_atb<<<dim3(6, 128), 256, 0, stream>>>(dbc, dt_proj_w, delta, dt_proj_b,
                                               8192, 384, 12, 44, 12, 384, 1, 2);
    // 7. selective scan (3-pass chunked)
    ssm_pass1<<<1536, 256, 0, stream>>>(delta, dbc, u, A_log, Pc, Hc);
    ssm_pass2<<<192, 256, 0, stream>>>(Pc, Hc, h0c);
    ssm_pass3<<<1536, 256, 0, stream>>>(delta, dbc, u, xz, A_log, Dp, h0c, y);
    // 8. out_proj
    gemm_atb<<<dim3(3, 128), 256, 0, stream>>>(y, out_proj_w, seqo, nullptr,
                                               8192, 192, 384, 384, 384, 192, 1, 0);
    // 9. decoder weight prep + seqo -> bf16
    f32_to_bf16_vec<<<1536, 256, 0, stream>>>(seqo, seqo_b);
    transpose_w_bf16<<<12288, 256, 0, stream>>>(deconv_w, W2b);
    rearrange_dcw<<<7, 256, 0, stream>>>(dec_conv_w, dwr);
    // 10. per-batch: MFMA deconv GEMM -> bf16 slab -> LDS-staged conv+sigmoid
    for (int b = 0; b < 8; ++b) {
        gemm_mfma_relu_bf16<<<dim3(128, 8), 256, 0, stream>>>(
            seqo_b + (size_t)b * 1024 * 192, W2b, Db16, deconv_b, 1024, 16384, 192);
        decconv_sigmoid2<<<1024, 256, 0, stream>>>(Db16, dwr, dec_conv_b, out, b);
    }
}

// Round 4
// 804.851 us; speedup vs baseline: 6.3472x; 1.3542x over previous
//
#include <hip/hip_runtime.h>
#include <math.h>

// ---------------------------------------------------------------------------
// VisionMambaDenoiser. Round 4: bf16 MFMA encoder GEMMs (fp32 gemm_atb was
// 118 us each, VALU-bound) + restructured scan (16 d/wave, 4 states/lane:
// fixes 4x line-overfetch, halves shuffles).
// ---------------------------------------------------------------------------

typedef short bf16x8 __attribute__((ext_vector_type(8)));
typedef float f32x4 __attribute__((ext_vector_type(4)));

__device__ inline unsigned short f2bf(float f) {
    unsigned int u = __float_as_uint(f);
    unsigned int r = (u + 0x7fff + ((u >> 16) & 1)) >> 16;   // RNE
    return (unsigned short)r;
}

// ---------------- flexible bf16 MFMA GEMM: C = A @ W^T (+bias) --------------
// A (M,K) bf16 row-major (lda=K), W (N,K) bf16 row-major. M%128==0, K%32==0,
// N arbitrary (guarded). Out fp32 or bf16 (ldc=N).
__global__ __launch_bounds__(256) void gemm_mfma_flex(
    const unsigned short* __restrict__ A, const unsigned short* __restrict__ W,
    void* __restrict__ Cout, const float* __restrict__ bias,
    int M, int N, int K, int out_bf16)
{
    __shared__ unsigned short As[128][48];
    __shared__ unsigned short Bs[128][48];
    const int tid = threadIdx.x;
    const int wave = tid >> 6, lane = tid & 63;
    const int wm = (wave & 1) * 64, wn = (wave >> 1) * 64;
    const int m0 = blockIdx.y * 128, n0 = blockIdx.x * 128;
    const int quad = lane >> 4, lr = lane & 15;
    const uint4 z4 = {0, 0, 0, 0};

    f32x4 acc[4][4];
    #pragma unroll
    for (int i = 0; i < 4; ++i)
        #pragma unroll
        for (int j = 0; j < 4; ++j)
            acc[i][j] = (f32x4){0.f, 0.f, 0.f, 0.f};

    const int r = tid >> 2, kq = tid & 3;
    for (int k0 = 0; k0 < K; k0 += 32) {
        #pragma unroll
        for (int half = 0; half < 2; ++half) {
            int rr = r + half * 64;
            *(uint4*)(&As[rr][kq * 8]) =
                *(const uint4*)(A + (size_t)(m0 + rr) * K + k0 + kq * 8);
            uint4 bv = z4;
            if (n0 + rr < N)
                bv = *(const uint4*)(W + (size_t)(n0 + rr) * K + k0 + kq * 8);
            *(uint4*)(&Bs[rr][kq * 8]) = bv;
        }
        __syncthreads();
        bf16x8 af[4], bfr[4];
        #pragma unroll
        for (int i = 0; i < 4; ++i) af[i] = *(const bf16x8*)(&As[wm + i * 16 + lr][quad * 8]);
        #pragma unroll
        for (int j = 0; j < 4; ++j) bfr[j] = *(const bf16x8*)(&Bs[wn + j * 16 + lr][quad * 8]);
        #pragma unroll
        for (int i = 0; i < 4; ++i)
            #pragma unroll
            for (int j = 0; j < 4; ++j)
                acc[i][j] = __builtin_amdgcn_mfma_f32_16x16x32_bf16(af[i], bfr[j], acc[i][j], 0, 0, 0);
        __syncthreads();
    }

    #pragma unroll
    for (int i = 0; i < 4; ++i) {
        int gm = m0 + wm + i * 16 + quad * 4;
        #pragma unroll
        for (int j = 0; j < 4; ++j) {
            int gn = n0 + wn + j * 16 + lr;
            if (gn >= N) continue;
            float bv = bias ? bias[gn] : 0.f;
            #pragma unroll
            for (int rr = 0; rr < 4; ++rr) {
                float v = acc[i][j][rr] + bv;
                if (out_bf16) ((unsigned short*)Cout)[(size_t)(gm + rr) * N + gn] = f2bf(v);
                else          ((float*)Cout)[(size_t)(gm + rr) * N + gn] = v;
            }
        }
    }
}

// ---------------- decoder MFMA GEMM: Db = bf16(relu(A @ W^T + bias[k])) -----
__global__ __launch_bounds__(256) void gemm_mfma_relu_bf16(
    const unsigned short* __restrict__ A, const unsigned short* __restrict__ W,
    unsigned short* __restrict__ C, const float* __restrict__ bias,
    int M, int N, int K)
{
    __shared__ unsigned short As[128][48];
    __shared__ unsigned short Bs[128][48];
    const int tid = threadIdx.x;
    const int wave = tid >> 6, lane = tid & 63;
    const int wm = (wave & 1) * 64, wn = (wave >> 1) * 64;
    const int m0 = blockIdx.y * 128, n0 = blockIdx.x * 128;
    const int quad = lane >> 4, lr = lane & 15;

    f32x4 acc[4][4];
    #pragma unroll
    for (int i = 0; i < 4; ++i)
        #pragma unroll
        for (int j = 0; j < 4; ++j)
            acc[i][j] = (f32x4){0.f, 0.f, 0.f, 0.f};

    const int r = tid >> 2, kq = tid & 3;
    for (int k0 = 0; k0 < K; k0 += 32) {
        #pragma unroll
        for (int half = 0; half < 2; ++half) {
            int rr = r + half * 64;
            *(uint4*)(&As[rr][kq * 8]) =
                *(const uint4*)(A + (size_t)(m0 + rr) * K + k0 + kq * 8);
            *(uint4*)(&Bs[rr][kq * 8]) =
                *(const uint4*)(W + (size_t)(n0 + rr) * K + k0 + kq * 8);
        }
        __syncthreads();
        bf16x8 af[4], bfr[4];
        #pragma unroll
        for (int i = 0; i < 4; ++i) af[i] = *(const bf16x8*)(&As[wm + i * 16 + lr][quad * 8]);
        #pragma unroll
        for (int j = 0; j < 4; ++j) bfr[j] = *(const bf16x8*)(&Bs[wn + j * 16 + lr][quad * 8]);
        #pragma unroll
        for (int i = 0; i < 4; ++i)
            #pragma unroll
            for (int j = 0; j < 4; ++j)
                acc[i][j] = __builtin_amdgcn_mfma_f32_16x16x32_bf16(af[i], bfr[j], acc[i][j], 0, 0, 0);
        __syncthreads();
    }

    #pragma unroll
    for (int i = 0; i < 4; ++i) {
        int gm = m0 + wm + i * 16 + quad * 4;
        #pragma unroll
        for (int j = 0; j < 4; ++j) {
            int gn = n0 + wn + j * 16 + lr;
            float bv = bias[gn & 63];
            #pragma unroll
            for (int rr = 0; rr < 4; ++rr) {
                float v = fmaxf(acc[i][j][rr] + bv, 0.f);
                C[(size_t)(gm + rr) * N + gn] = f2bf(v);
            }
        }
    }
}

// ---------------- im2col of 16x16 patches -> bf16 ---------------------------
__global__ __launch_bounds__(256) void im2col_bf16(const float* __restrict__ x,
                                                   unsigned short* __restrict__ P)
{
    int idx = blockIdx.x * 256 + threadIdx.x;   // 8192*768
    int col = idx % 768;
    int row = idx / 768;
    int b = row >> 10;
    int l = row & 1023;
    int h = l >> 5, w = l & 31;
    int c = col >> 8;
    int p = (col >> 4) & 15, q = col & 15;
    P[idx] = f2bf(x[((size_t)(b * 3 + c) * 512 + (h * 16 + p)) * 512 + (w * 16 + q)]);
}

// ---------------- generic fp32 -> bf16 convert ------------------------------
__global__ void f2b_n(const float* __restrict__ src, unsigned short* __restrict__ dst, int n)
{
    int i = blockIdx.x * 256 + threadIdx.x;
    if (i < n) dst[i] = f2bf(src[i]);
}

// ---------------- depthwise causal conv1d + silu (dual out) -----------------
__global__ __launch_bounds__(256) void conv1d_silu(const float* __restrict__ xz,
                                                   const float* __restrict__ cw,
                                                   const float* __restrict__ cb,
                                                   float* __restrict__ u32,
                                                   unsigned short* __restrict__ u16)
{
    int idx = blockIdx.x * 256 + threadIdx.x;   // 8192*384
    int d = idx % 384;
    int row = idx / 384;
    int l = row & 1023;
    float acc = cb[d];
    #pragma unroll
    for (int j = 0; j < 4; ++j) {
        int ll = l - 3 + j;
        if (ll >= 0) acc += xz[(size_t)(row - 3 + j) * 768 + d] * cw[d * 4 + j];
    }
    float s = acc / (1.f + __expf(-acc));
    u32[idx] = s;
    u16[idx] = f2bf(s);
}

// ---------------- dt_proj + softplus (K=12 vector kernel) -------------------
__global__ __launch_bounds__(256) void dtproj_softplus(const float* __restrict__ dbc,
                                                       const float* __restrict__ dtw,
                                                       const float* __restrict__ dtb,
                                                       float* __restrict__ delta)
{
    int idx = blockIdx.x * 256 + threadIdx.x;   // 8192*384
    int n = idx % 384, m = idx / 384;
    const float* row = dbc + (size_t)m * 44;
    const float* wr  = dtw + n * 12;
    float acc = dtb[n];
    #pragma unroll
    for (int j = 0; j < 12; ++j) acc = fmaf(row[j], wr[j], acc);
    delta[idx] = (acc > 20.f) ? acc : log1pf(__expf(acc));
}

// ---------------- selective scan, 3-pass chunked ----------------------------
// 16 chunks of 64. Block 256 = 64 d x 4 n4 (each lane holds states n4*4..+3).
// Wave = 16 consecutive d x 4 n4 -> delta/u loads are full 64B lines.
// Grid (16 c, 6 dg, 8 b); blk = (b*6+dg)*16+c; Pc/Hc/h0c idx = blk*1024+tid*4+j.
__global__ __launch_bounds__(256) void ssm_pass1(const float* __restrict__ delta,
                                                 const float* __restrict__ dbc,
                                                 const float* __restrict__ u,
                                                 const float* __restrict__ A_log,
                                                 float* __restrict__ Pc,
                                                 float* __restrict__ Hc)
{
    const int tid = threadIdx.x;
    const int n4 = tid & 3, dloc = tid >> 2;
    const int c = blockIdx.x, dg = blockIdx.y, b = blockIdx.z;
    const int d = dg * 64 + dloc;
    const int blk = (b * 6 + dg) * 16 + c;
    f32x4 A4 = *(const f32x4*)(A_log + d * 16 + n4 * 4);
    float Aa[4];
    #pragma unroll
    for (int j = 0; j < 4; ++j) Aa[j] = -__expf(A4[j]);
    const float* dp = delta + (size_t)(b * 1024) * 384 + d;
    const float* up = u     + (size_t)(b * 1024) * 384 + d;
    const float* bp = dbc   + (size_t)(b * 1024) * 44;
    float P[4] = {1.f, 1.f, 1.f, 1.f}, H[4] = {0.f, 0.f, 0.f, 0.f};
    const int l0 = c * 64;
    for (int l = l0; l < l0 + 64; ++l) {
        float dlv = dp[(size_t)l * 384];
        float ulv = up[(size_t)l * 384];
        f32x4 B4 = *(const f32x4*)(bp + (size_t)l * 44 + 12 + n4 * 4);
        float du = dlv * ulv;
        #pragma unroll
        for (int j = 0; j < 4; ++j) {
            float a = __expf(dlv * Aa[j]);
            P[j] *= a;
            H[j] = fmaf(a, H[j], du * B4[j]);
        }
    }
    size_t o = ((size_t)blk * 256 + tid) * 4;
    *(f32x4*)(Pc + o) = (f32x4){P[0], P[1], P[2], P[3]};
    *(f32x4*)(Hc + o) = (f32x4){H[0], H[1], H[2], H[3]};
}

__global__ __launch_bounds__(256) void ssm_pass2(const float* __restrict__ Pc,
                                                 const float* __restrict__ Hc,
                                                 float* __restrict__ h0c)
{
    int t = blockIdx.x * 256 + threadIdx.x;    // 48*1024 = 49152
    int grp = t >> 10, dn = t & 1023;
    float h = 0.f;
    #pragma unroll
    for (int c = 0; c < 16; ++c) {
        size_t idx = ((size_t)(grp * 16 + c)) * 1024 + dn;
        h0c[idx] = h;
        h = fmaf(Pc[idx], h, Hc[idx]);
    }
}

__global__ __launch_bounds__(256) void ssm_pass3(const float* __restrict__ delta,
                                                 const float* __restrict__ dbc,
                                                 const float* __restrict__ u,
                                                 const float* __restrict__ xz,
                                                 const float* __restrict__ A_log,
                                                 const float* __restrict__ Dp,
                                                 const float* __restrict__ h0c,
                                                 unsigned short* __restrict__ y16)
{
    const int tid = threadIdx.x;
    const int n4 = tid & 3, dloc = tid >> 2;
    const int c = blockIdx.x, dg = blockIdx.y, b = blockIdx.z;
    const int d = dg * 64 + dloc;
    const int blk = (b * 6 + dg) * 16 + c;
    f32x4 A4 = *(const f32x4*)(A_log + d * 16 + n4 * 4);
    float Aa[4];
    #pragma unroll
    for (int j = 0; j < 4; ++j) Aa[j] = -__expf(A4[j]);
    float Dv = Dp[d];
    const float* dp = delta + (size_t)(b * 1024) * 384 + d;
    const float* up = u     + (size_t)(b * 1024) * 384 + d;
    const float* bp = dbc   + (size_t)(b * 1024) * 44;
    const float* zp = xz    + (size_t)(b * 1024) * 768 + 384 + d;
    unsigned short* yp = y16 + (size_t)(b * 1024) * 384 + d;
    f32x4 h4 = *(const f32x4*)(h0c + ((size_t)blk * 256 + tid) * 4);
    float H[4] = {h4[0], h4[1], h4[2], h4[3]};
    const int l0 = c * 64;
    for (int l = l0; l < l0 + 64; ++l) {
        float dlv = dp[(size_t)l * 384];
        float ulv = up[(size_t)l * 384];
        f32x4 B4 = *(const f32x4*)(bp + (size_t)l * 44 + 12 + n4 * 4);
        f32x4 C4 = *(const f32x4*)(bp + (size_t)l * 44 + 28 + n4 * 4);
        float du = dlv * ulv;
        float part = 0.f;
        #pragma unroll
        for (int j = 0; j < 4; ++j) {
            float a = __expf(dlv * Aa[j]);
            H[j] = fmaf(a, H[j], du * B4[j]);
            part = fmaf(H[j], C4[j], part);
        }
        part += __shfl_xor(part, 1, 4);
        part += __shfl_xor(part, 2, 4);
        if (n4 == 0) {
            float z = zp[(size_t)l * 768];
            float sz = z / (1.f + __expf(-z));
            yp[(size_t)l * 384] = f2bf((part + ulv * Dv) * sz);
        }
    }
}

// deconv_w (192,64,16,16) fp32 -> W2b[n'][c] bf16, n' = (p*16+q)*64 + k
__global__ __launch_bounds__(256) void transpose_w_bf16(const float* __restrict__ src,
                                                        unsigned short* __restrict__ dst)
{
    int idx = blockIdx.x * 256 + threadIdx.x;  // 16384*192
    int c = idx % 192;
    int np = idx / 192;
    int k = np & 63;
    int pq = np >> 6;
    dst[idx] = f2bf(src[(size_t)c * 16384 + k * 256 + pq]);
}

// dec_conv_w (3,64,3,3) -> dwr[((co*3+dy)*3+dx)*64 + k]
__global__ void rearrange_dcw(const float* __restrict__ src, float* __restrict__ dst)
{
    int i = blockIdx.x * 256 + threadIdx.x;
    if (i >= 1728) return;
    int k = i & 63;
    int r = i >> 6;
    int co = r / 9;
    int dydx = r % 9;
    int dy = dydx / 3, dx = dydx % 3;
    dst[i] = src[((co * 64 + k) * 3 + dy) * 3 + dx];
}

// ---------------- LDS-staged 3x3 conv (64->3) + bias + sigmoid --------------
__global__ __launch_bounds__(256) void decconv_sigmoid2(
    const unsigned short* __restrict__ Db, const float* __restrict__ dwr,
    const float* __restrict__ dcb, float* __restrict__ out, int b)
{
    __shared__ unsigned short ds[18 * 18 * 72];
    const int t = threadIdx.x;
    const int pidx = blockIdx.x;            // h*32 + w
    const int ph = pidx >> 5, pw = pidx & 31;
    const uint4 z4 = {0, 0, 0, 0};

    const unsigned short* base = Db + ((size_t)pidx << 14);
    #pragma unroll
    for (int s = 0; s < 8; ++s) {
        int f = s * 256 + t;
        int k8 = f & 7, pq = f >> 3;
        int p = pq >> 4, q = pq & 15;
        *(uint4*)&ds[((p + 1) * 18 + q + 1) * 72 + k8 * 8] =
            *(const uint4*)(base + pq * 64 + k8 * 8);
    }
    {
        int k8 = t & 7, e = (t >> 3) & 15;
        if (t < 128) {
            uint4 v = z4;
            if (ph > 0) v = *(const uint4*)(Db + ((size_t)(pidx - 32) << 14) + (240 + e) * 64 + k8 * 8);
            *(uint4*)&ds[(0 * 18 + e + 1) * 72 + k8 * 8] = v;
        } else {
            uint4 v = z4;
            if (ph < 31) v = *(const uint4*)(Db + ((size_t)(pidx + 32) << 14) + e * 64 + k8 * 8);
            *(uint4*)&ds[(17 * 18 + e + 1) * 72 + k8 * 8] = v;
        }
        if (t < 128) {
            uint4 v = z4;
            if (pw > 0) v = *(const uint4*)(Db + ((size_t)(pidx - 1) << 14) + (e * 16 + 15) * 64 + k8 * 8);
            *(uint4*)&ds[((e + 1) * 18 + 0) * 72 + k8 * 8] = v;
        } else {
            uint4 v = z4;
            if (pw < 31) v = *(const uint4*)(Db + ((size_t)(pidx + 1) << 14) + (e * 16) * 64 + k8 * 8);
            *(uint4*)&ds[((e + 1) * 18 + 17) * 72 + k8 * 8] = v;
        }
        if (t < 32) {
            int c = t >> 3;
            int dh = (c >> 1) * 2 - 1, dw = (c & 1) * 2 - 1;
            int nh = ph + dh, nw = pw + dw;
            int sp = dh < 0 ? 15 : 0, sq = dw < 0 ? 15 : 0;
            uint4 v = z4;
            if (nh >= 0 && nh < 32 && nw >= 0 && nw < 32)
                v = *(const uint4*)(Db + ((size_t)(nh * 32 + nw) << 14) + (sp * 16 + sq) * 64 + k8 * 8);
            int dy = dh < 0 ? 0 : 17, dx = dw < 0 ? 0 : 17;
            *(uint4*)&ds[(dy * 18 + dx) * 72 + k8 * 8] = v;
        }
    }
    __syncthreads();

    const int px = t & 15, py = t >> 4;
    float a0 = dcb[0], a1 = dcb[1], a2 = dcb[2];
    for (int dy = 0; dy < 3; ++dy)
        for (int dx = 0; dx < 3; ++dx) {
            const unsigned short* cell = &ds[((py + dy) * 18 + (px + dx)) * 72];
            const float* w0 = dwr + (0 * 9 + dy * 3 + dx) * 64;
            const float* w1 = dwr + (1 * 9 + dy * 3 + dx) * 64;
            const float* w2 = dwr + (2 * 9 + dy * 3 + dx) * 64;
            #pragma unroll
            for (int k8 = 0; k8 < 8; ++k8) {
                uint4 v = *(const uint4*)(cell + k8 * 8);
                unsigned int uu[4] = {v.x, v.y, v.z, v.w};
                #pragma unroll
                for (int m = 0; m < 4; ++m) {
                    float flo = __uint_as_float(uu[m] << 16);
                    float fhi = __uint_as_float(uu[m] & 0xffff0000u);
                    int k = k8 * 8 + m * 2;
                    a0 += flo * w0[k] + fhi * w0[k + 1];
                    a1 += flo * w1[k] + fhi * w1[k + 1];
                    a2 += flo * w2[k] + fhi * w2[k + 1];
                }
            }
        }

    int Y = ph * 16 + py, X = pw * 16 + px;
    size_t o = (size_t)(b * 3) * 262144 + (size_t)Y * 512 + X;
    out[o]          = 1.f / (1.f + __expf(-a0));
    out[o + 262144] = 1.f / (1.f + __expf(-a1));
    out[o + 524288] = 1.f / (1.f + __expf(-a2));
}

// ---------------------------------------------------------------------------
// Workspace (float units). Used: 19,855,296 floats = 79.4 MB (ws has 88.1 MB).
// Db16 (decoder) aliases [0, 8388608): delta/dbc/xz dead by then.
// ---------------------------------------------------------------------------
#define WS_P16      0            // 1572864 (ushort), dead after patch gemm
#define WS_DELTA    0            // 3145728, dt_proj..pass3
#define WS_SEQ16    3145728      // 786432, dead after in_proj
#define WS_DBC      3145728      // 360448, x_proj..pass3 (aliases dead seq16)
#define WS_XZ       3932160      // 6291456, in_proj..pass3
#define WS_U32      10223616     // 3145728, conv1d..pass3
#define WS_U16      13369344     // 786432*2B? = 1572864 floats region, conv1d..x_proj
#define WS_Y16      13369344     // 786432 ushort-floats, pass3..out_proj (aliases u16)
#define WS_PC       14942208     // 786432
#define WS_HC       15728640     // 786432
#define WS_H0C      16515072     // 786432
#define WS_SEQOB    17301504     // 786432 (bf16 8192x192)
#define WS_W2       18087936     // 1572864 (bf16 16384x192)
#define WS_WP16     19660800     // 73728
#define WS_WI16     19734528     // 73728
#define WS_WX16     19808256     // 8448
#define WS_WO16     19816704     // 36864
#define WS_DWR      19853568     // 1728
#define WS_DB       0            // 8388608 (decoder phase)

extern "C" void kernel_launch(void* const* d_in, const int* in_sizes, int n_in,
                              void* d_out, int out_size, void* d_ws, size_t ws_size,
                              hipStream_t stream)
{
    const float* x         = (const float*)d_in[0];
    const float* patch_w   = (const float*)d_in[1];
    const float* patch_b   = (const float*)d_in[2];
    const float* in_proj_w = (const float*)d_in[3];
    const float* conv1d_w  = (const float*)d_in[4];
    const float* conv1d_b  = (const float*)d_in[5];
    const float* x_proj_w  = (const float*)d_in[6];
    const float* dt_proj_w = (const float*)d_in[7];
    const float* dt_proj_b = (const float*)d_in[8];
    const float* A_log     = (const float*)d_in[9];
    const float* Dp        = (const float*)d_in[10];
    const float* out_proj_w= (const float*)d_in[11];
    const float* deconv_w  = (const float*)d_in[12];
    const float* deconv_b  = (const float*)d_in[13];
    const float* dec_conv_w= (const float*)d_in[14];
    const float* dec_conv_b= (const float*)d_in[15];
    float* out = (float*)d_out;
    float* ws  = (float*)d_ws;

    unsigned short* P16   = (unsigned short*)(ws + WS_P16);
    float*          delta = ws + WS_DELTA;
    unsigned short* seq16 = (unsigned short*)(ws + WS_SEQ16);
    float*          dbc   = ws + WS_DBC;
    float*          xz    = ws + WS_XZ;
    float*          u32   = ws + WS_U32;
    unsigned short* u16   = (unsigned short*)(ws + WS_U16);
    unsigned short* y16   = (unsigned short*)(ws + WS_Y16);
    float*          Pc    = ws + WS_PC;
    float*          Hc    = ws + WS_HC;
    float*          h0c   = ws + WS_H0C;
    unsigned short* seqo_b= (unsigned short*)(ws + WS_SEQOB);
    unsigned short* W2b   = (unsigned short*)(ws + WS_W2);
    unsigned short* wp16  = (unsigned short*)(ws + WS_WP16);
    unsigned short* wi16  = (unsigned short*)(ws + WS_WI16);
    unsigned short* wx16  = (unsigned short*)(ws + WS_WX16);
    unsigned short* wo16  = (unsigned short*)(ws + WS_WO16);
    float*          dwr   = ws + WS_DWR;
    unsigned short* Db16  = (unsigned short*)(ws + WS_DB);

    // 1. im2col -> bf16 P
    im2col_bf16<<<24576, 256, 0, stream>>>(x, P16);
    // 2. weight -> bf16 converts
    f2b_n<<<576, 256, 0, stream>>>(patch_w,    wp16, 147456);
    f2b_n<<<576, 256, 0, stream>>>(in_proj_w,  wi16, 147456);
    f2b_n<<<66,  256, 0, stream>>>(x_proj_w,   wx16, 16896);
    f2b_n<<<288, 256, 0, stream>>>(out_proj_w, wo16, 73728);
    // 3. patch embedding: (8192,768)@(192,768)^T + b -> seq16 bf16
    gemm_mfma_flex<<<dim3(2, 64), 256, 0, stream>>>(P16, wp16, seq16, patch_b,
                                                    8192, 192, 768, 1);
    // 4. in_proj: (8192,192)@(768,192)^T -> xz fp32
    gemm_mfma_flex<<<dim3(6, 64), 256, 0, stream>>>(seq16, wi16, xz, nullptr,
                                                    8192, 768, 192, 0);
    // 5. conv1d + silu -> u32 + u16
    conv1d_silu<<<12288, 256, 0, stream>>>(xz, conv1d_w, conv1d_b, u32, u16);
    // 6. x_proj: (8192,384)@(44,384)^T -> dbc fp32
    gemm_mfma_flex<<<dim3(1, 64), 256, 0, stream>>>(u16, wx16, dbc, nullptr,
                                                    8192, 44, 384, 0);
    // 7. dt_proj + softplus -> delta fp32
    dtproj_softplus<<<12288, 256, 0, stream>>>(dbc, dt_proj_w, dt_proj_b, delta);
    // 8. selective scan (3-pass, 16 chunks of 64)
    ssm_pass1<<<dim3(16, 6, 8), 256, 0, stream>>>(delta, dbc, u32, A_log, Pc, Hc);
    ssm_pass2<<<192, 256, 0, stream>>>(Pc, Hc, h0c);
    ssm_pass3<<<dim3(16, 6, 8), 256, 0, stream>>>(delta, dbc, u32, xz, A_log, Dp, h0c, y16);
    // 9. out_proj: (8192,384)@(192,384)^T -> seqo_b bf16 (direct)
    gemm_mfma_flex<<<dim3(2, 64), 256, 0, stream>>>(y16, wo16, seqo_b, nullptr,
                                                    8192, 192, 384, 1);
    // 10. decoder weight prep
    transpose_w_bf16<<<12288, 256, 0, stream>>>(deconv_w, W2b);
    rearrange_dcw<<<7, 256, 0, stream>>>(dec_conv_w, dwr);
    // 11. per-batch: MFMA deconv GEMM -> bf16 slab -> LDS-staged conv+sigmoid
    for (int b = 0; b < 8; ++b) {
        gemm_mfma_relu_bf16<<<dim3(128, 8), 256, 0, stream>>>(
            seqo_b + (size_t)b * 1024 * 192, W2b, Db16, deconv_b, 1024, 16384, 192);
        decconv_sigmoid2<<<1024, 256, 0, stream>>>(Db16, dwr, dec_conv_b, out, b);
    }
}